// Round 6
// baseline (60.071 us; speedup 1.0000x reference)
//
#include <hip/hip_runtime.h>
#include <math.h>

// B=4096 rows, C=128, labels {0,1}. loss = bce + wlsep.
//   bce   = mean(softplus(label ? -x : x))
//   wlsep = (1/Npos) * sum_{j pos} softplus(L - x_j),  L = m + log(T),
//           m = max_neg x_i, T = sum_neg exp(x_i - m)
// R5 lesson: body work is ~500 cyc/wave; what's left is latency structure.
// R6: dedicated finalizer block (spins from t=0, overlapping worker time) +
// parallel 3-slot spin loads (1 round trip/retry, not 3 serialized).
// Init-free protocol: slots are u64 (lo=bits(v), hi=~lo), relaxed device-scope
// atomics; 0xAA poison and zeros both fail hi==~lo.

#define C_DIM 128
#define TPB   256    // 4 waves/block; 4 rows/wave -> 16 rows/block

typedef unsigned int u32;
typedef unsigned long long u64;

__device__ __forceinline__ float softplus_fast(float z) {
    // log(1+exp(z)) = max(z,0) + log(1 + exp(-|z|)); exact 0 at z=-inf
    return fmaxf(z, 0.0f) + __logf(1.0f + __expf(-fabsf(z)));
}

__device__ __forceinline__ u64 pack_checked(float f) {
    u32 v = __float_as_uint(f);
    return (u64)v | ((u64)(~v) << 32);
}
__device__ __forceinline__ bool slot_ok(u64 v) { return (u32)(v >> 32) == ~(u32)v; }

__global__ __launch_bounds__(TPB) void bce_wlsep_onepass(
        const float* __restrict__ x, const int* __restrict__ t,
        u64* __restrict__ slots,      // [3 * nblocks] in d_ws, uninitialized
        float* __restrict__ out, int B, int nblocks, float inv_BC) {
    const int wave = threadIdx.x >> 6;
    const int lane = threadIdx.x & 63;
    __shared__ float s[3][4];

    if ((int)blockIdx.x == nblocks) {
        // ================= dedicated finalizer block =================
        // Spins from t=0; readback overlaps worker execution.
        float fb = 0.f, fw = 0.f, fp = 0.f;
        for (int i = threadIdx.x; i < nblocks; i += TPB) {
            u64 v0 = __hip_atomic_load(&slots[3*i+0], __ATOMIC_RELAXED, __HIP_MEMORY_SCOPE_AGENT);
            u64 v1 = __hip_atomic_load(&slots[3*i+1], __ATOMIC_RELAXED, __HIP_MEMORY_SCOPE_AGENT);
            u64 v2 = __hip_atomic_load(&slots[3*i+2], __ATOMIC_RELAXED, __HIP_MEMORY_SCOPE_AGENT);
            while (!(slot_ok(v0) && slot_ok(v1) && slot_ok(v2))) {
                // re-issue all failed loads together: one round trip per retry
                if (!slot_ok(v0)) v0 = __hip_atomic_load(&slots[3*i+0], __ATOMIC_RELAXED, __HIP_MEMORY_SCOPE_AGENT);
                if (!slot_ok(v1)) v1 = __hip_atomic_load(&slots[3*i+1], __ATOMIC_RELAXED, __HIP_MEMORY_SCOPE_AGENT);
                if (!slot_ok(v2)) v2 = __hip_atomic_load(&slots[3*i+2], __ATOMIC_RELAXED, __HIP_MEMORY_SCOPE_AGENT);
            }
            fb += __uint_as_float((u32)v0);
            fw += __uint_as_float((u32)v1);
            fp += __uint_as_float((u32)v2);
        }
        #pragma unroll
        for (int off = 32; off; off >>= 1) {
            fb += __shfl_xor(fb, off, 64);
            fw += __shfl_xor(fw, off, 64);
            fp += __shfl_xor(fp, off, 64);
        }
        if (lane == 0) { s[0][wave] = fb; s[1][wave] = fw; s[2][wave] = fp; }
        __syncthreads();
        if (threadIdx.x == 0) {
            float b = s[0][0] + s[0][1] + s[0][2] + s[0][3];
            float w = s[1][0] + s[1][1] + s[1][2] + s[1][3];
            float p = s[2][0] + s[2][1] + s[2][2] + s[2][3];
            out[0] = b * inv_BC + w / p;
        }
        return;
    }

    // ================= worker block =================
    const int half = lane >> 5;       // which row of the pair
    const int sub  = lane & 31;       // float4 group within the row
    const int base = (blockIdx.x * 4 + wave) * 4;   // 4 rows per wave

    const float4* xq = (const float4*)x;
    const int4*   tq = (const int4*)t;

    float4 xv[2]; int4 tv[2];
    #pragma unroll
    for (int it = 0; it < 2; ++it) {
        const int r = base + 2 * it + half;
        if (r < B) {
            xv[it] = xq[(size_t)r * (C_DIM / 4) + sub];
            tv[it] = tq[(size_t)r * (C_DIM / 4) + sub];
        } else {
            xv[it] = make_float4(-INFINITY, -INFINITY, -INFINITY, -INFINITY);
            tv[it] = make_int4(0, 0, 0, 0);   // neutral row: contributes nothing
        }
    }

    float bce = 0.f, wl = 0.f, pos = 0.f;
    #pragma unroll
    for (int it = 0; it < 2; ++it) {
        const float xe[4] = {xv[it].x, xv[it].y, xv[it].z, xv[it].w};
        const int   te[4] = {tv[it].x, tv[it].y, tv[it].z, tv[it].w};

        float m = -INFINITY;
        #pragma unroll
        for (int e = 0; e < 4; ++e) {
            bce += softplus_fast(te[e] ? -xe[e] : xe[e]);
            if (!te[e]) m = fmaxf(m, xe[e]);
        }
        #pragma unroll
        for (int off = 16; off; off >>= 1) m = fmaxf(m, __shfl_xor(m, off, 64));

        float T = 0.f;
        #pragma unroll
        for (int e = 0; e < 4; ++e)
            if (!te[e]) T += __expf(xe[e] - m);
        #pragma unroll
        for (int off = 16; off; off >>= 1) T += __shfl_xor(T, off, 64);

        const float L = m + __logf(T);   // -inf if row has no negatives
        #pragma unroll
        for (int e = 0; e < 4; ++e) {
            if (te[e]) { wl += softplus_fast(L - xe[e]); pos += 1.f; }
        }
    }

    #pragma unroll
    for (int off = 32; off; off >>= 1) {
        bce += __shfl_xor(bce, off, 64);
        wl  += __shfl_xor(wl,  off, 64);
        pos += __shfl_xor(pos, off, 64);
    }
    if (lane == 0) { s[0][wave] = bce; s[1][wave] = wl; s[2][wave] = pos; }
    __syncthreads();
    if (threadIdx.x == 0) {
        float b = s[0][0] + s[0][1] + s[0][2] + s[0][3];
        float w = s[1][0] + s[1][1] + s[1][2] + s[1][3];
        float p = s[2][0] + s[2][1] + s[2][2] + s[2][3];
        __hip_atomic_store(&slots[3*blockIdx.x+0], pack_checked(b), __ATOMIC_RELAXED, __HIP_MEMORY_SCOPE_AGENT);
        __hip_atomic_store(&slots[3*blockIdx.x+1], pack_checked(w), __ATOMIC_RELAXED, __HIP_MEMORY_SCOPE_AGENT);
        __hip_atomic_store(&slots[3*blockIdx.x+2], pack_checked(p), __ATOMIC_RELAXED, __HIP_MEMORY_SCOPE_AGENT);
    }
}

extern "C" void kernel_launch(void* const* d_in, const int* in_sizes, int n_in,
                              void* d_out, int out_size, void* d_ws, size_t ws_size,
                              hipStream_t stream) {
    const float* x = (const float*)d_in[0];
    const int*   t = (const int*)d_in[1];
    float* out = (float*)d_out;
    u64* slots = (u64*)d_ws;   // 3 * nblocks u64, init-free protocol

    const int total = in_sizes[0];
    const int B = total / C_DIM;
    const int blocks = (B + 15) / 16;   // 16 rows per worker block

    // grid = workers + 1 dedicated finalizer (block index == blocks)
    bce_wlsep_onepass<<<blocks + 1, TPB, 0, stream>>>(x, t, slots, out,
                                                      B, blocks, 1.0f / (float)total);
}

// Round 7
// 58.849 us; speedup vs baseline: 1.0208x; 1.0208x over previous
//
#include <hip/hip_runtime.h>
#include <math.h>

// B=4096 rows, C=128, labels {0,1}. loss = bce + wlsep.
//   bce   = mean(softplus(label ? -x : x))
//   wlsep = (1/Npos) * sum_{j pos} softplus(L - x_j),  L = m + log(T),
//           m = max_neg x_i, T = sum_neg exp(x_i - m)
// R6 lesson: dedicated spinning finalizer regressed ~1us (spin traffic
// contends with worker slot stores); kernel-side deltas are now inside the
// bench noise band. This is the best-measured structure (R5, 58.98us):
// single dispatch, last-dispatched block finalizes, float4 loads (2 rows per
// wave in 32-lane halves), row-level L = m + log T, fast intrinsics.
// Init-free protocol: slots are u64 (lo=bits(v), hi=~lo), relaxed device-
// scope atomics; 0xAA poison and zeros both fail hi==~lo.
// Wall-time budget at this point: ~40us harness d_ws poison fill + ~13us
// input-restore/poison/gaps + ~5us kernel => ~59us floor.

#define C_DIM 128
#define TPB   256    // 4 waves/block; 4 rows/wave -> 16 rows/block -> 256 blocks

typedef unsigned int u32;
typedef unsigned long long u64;

__device__ __forceinline__ float softplus_fast(float z) {
    // log(1+exp(z)) = max(z,0) + log(1 + exp(-|z|)); exact 0 at z=-inf
    return fmaxf(z, 0.0f) + __logf(1.0f + __expf(-fabsf(z)));
}

__device__ __forceinline__ u64 pack_checked(float f) {
    u32 v = __float_as_uint(f);
    return (u64)v | ((u64)(~v) << 32);
}

__global__ __launch_bounds__(TPB) void bce_wlsep_onepass(
        const float* __restrict__ x, const int* __restrict__ t,
        u64* __restrict__ slots,      // [3 * nblocks] in d_ws, uninitialized
        float* __restrict__ out, int B, int nblocks, float inv_BC) {
    const int wave = threadIdx.x >> 6;
    const int lane = threadIdx.x & 63;
    const int half = lane >> 5;       // which row of the pair
    const int sub  = lane & 31;       // float4 group within the row
    const int base = (blockIdx.x * 4 + wave) * 4;   // 4 rows per wave

    const float4* xq = (const float4*)x;
    const int4*   tq = (const int4*)t;

    // ---- prefetch: 2 pair-iterations, 4 loads in flight per lane ----
    float4 xv[2]; int4 tv[2];
    #pragma unroll
    for (int it = 0; it < 2; ++it) {
        const int r = base + 2 * it + half;
        if (r < B) {
            xv[it] = xq[(size_t)r * (C_DIM / 4) + sub];
            tv[it] = tq[(size_t)r * (C_DIM / 4) + sub];
        } else {
            // neutral row: all "negatives" at -inf -> zero contribution
            xv[it] = make_float4(-INFINITY, -INFINITY, -INFINITY, -INFINITY);
            tv[it] = make_int4(0, 0, 0, 0);
        }
    }

    float bce = 0.f, wl = 0.f, pos = 0.f;
    #pragma unroll
    for (int it = 0; it < 2; ++it) {
        const float xe[4] = {xv[it].x, xv[it].y, xv[it].z, xv[it].w};
        const int   te[4] = {tv[it].x, tv[it].y, tv[it].z, tv[it].w};

        // bce + row max over negatives (local)
        float m = -INFINITY;
        #pragma unroll
        for (int e = 0; e < 4; ++e) {
            bce += softplus_fast(te[e] ? -xe[e] : xe[e]);
            if (!te[e]) m = fmaxf(m, xe[e]);
        }
        // butterfly max within the 32-lane half
        #pragma unroll
        for (int off = 16; off; off >>= 1) m = fmaxf(m, __shfl_xor(m, off, 64));

        // T = sum over negatives of exp(x - m)
        float T = 0.f;
        #pragma unroll
        for (int e = 0; e < 4; ++e)
            if (!te[e]) T += __expf(xe[e] - m);
        #pragma unroll
        for (int off = 16; off; off >>= 1) T += __shfl_xor(T, off, 64);

        // L = m + log(T); no negatives -> L = -inf -> softplus(-inf) = 0
        const float L = m + __logf(T);
        #pragma unroll
        for (int e = 0; e < 4; ++e) {
            if (te[e]) { wl += softplus_fast(L - xe[e]); pos += 1.f; }
        }
    }

    // ---- full-wave reduce (sums both halves = both rows) ----
    #pragma unroll
    for (int off = 32; off; off >>= 1) {
        bce += __shfl_xor(bce, off, 64);
        wl  += __shfl_xor(wl,  off, 64);
        pos += __shfl_xor(pos, off, 64);
    }

    // ---- block reduce across 4 waves ----
    __shared__ float s[3][4];
    if (lane == 0) { s[0][wave] = bce; s[1][wave] = wl; s[2][wave] = pos; }
    __syncthreads();
    if (threadIdx.x == 0) {
        float b = s[0][0] + s[0][1] + s[0][2] + s[0][3];
        float w = s[1][0] + s[1][1] + s[1][2] + s[1][3];
        float p = s[2][0] + s[2][1] + s[2][2] + s[2][3];
        __hip_atomic_store(&slots[3*blockIdx.x+0], pack_checked(b), __ATOMIC_RELAXED, __HIP_MEMORY_SCOPE_AGENT);
        __hip_atomic_store(&slots[3*blockIdx.x+1], pack_checked(w), __ATOMIC_RELAXED, __HIP_MEMORY_SCOPE_AGENT);
        __hip_atomic_store(&slots[3*blockIdx.x+2], pack_checked(p), __ATOMIC_RELAXED, __HIP_MEMORY_SCOPE_AGENT);
    }

    // ---- last-dispatched block finalizes ----
    if (blockIdx.x != (unsigned)(nblocks - 1)) return;

    float fb = 0.f, fw = 0.f, fp = 0.f;
    for (int i = threadIdx.x; i < nblocks; i += TPB) {
        u64 v;
        do { v = __hip_atomic_load(&slots[3*i+0], __ATOMIC_RELAXED, __HIP_MEMORY_SCOPE_AGENT); }
        while ((u32)(v >> 32) != ~(u32)v);
        fb += __uint_as_float((u32)v);
        do { v = __hip_atomic_load(&slots[3*i+1], __ATOMIC_RELAXED, __HIP_MEMORY_SCOPE_AGENT); }
        while ((u32)(v >> 32) != ~(u32)v);
        fw += __uint_as_float((u32)v);
        do { v = __hip_atomic_load(&slots[3*i+2], __ATOMIC_RELAXED, __HIP_MEMORY_SCOPE_AGENT); }
        while ((u32)(v >> 32) != ~(u32)v);
        fp += __uint_as_float((u32)v);
    }
    #pragma unroll
    for (int off = 32; off; off >>= 1) {
        fb += __shfl_xor(fb, off, 64);
        fw += __shfl_xor(fw, off, 64);
        fp += __shfl_xor(fp, off, 64);
    }
    __syncthreads();                 // whole block is here; reuse s[]
    if (lane == 0) { s[0][wave] = fb; s[1][wave] = fw; s[2][wave] = fp; }
    __syncthreads();
    if (threadIdx.x == 0) {
        float b = s[0][0] + s[0][1] + s[0][2] + s[0][3];
        float w = s[1][0] + s[1][1] + s[1][2] + s[1][3];
        float p = s[2][0] + s[2][1] + s[2][2] + s[2][3];
        out[0] = b * inv_BC + w / p;
    }
}

extern "C" void kernel_launch(void* const* d_in, const int* in_sizes, int n_in,
                              void* d_out, int out_size, void* d_ws, size_t ws_size,
                              hipStream_t stream) {
    const float* x = (const float*)d_in[0];
    const int*   t = (const int*)d_in[1];
    float* out = (float*)d_out;
    u64* slots = (u64*)d_ws;   // 3 * nblocks u64, init-free protocol

    const int total = in_sizes[0];
    const int B = total / C_DIM;
    const int blocks = (B + 15) / 16;   // 16 rows/block -> 256 at B=4096

    bce_wlsep_onepass<<<blocks, TPB, 0, stream>>>(x, t, slots, out,
                                                  B, blocks, 1.0f / (float)total);
}